// Round 5
// baseline (1805.349 us; speedup 1.0000x reference)
//
#include <hip/hip_runtime.h>
#include <math.h>

#define B_DIM 16
#define S_LEN 4096
#define C_DIM 512
#define TMAXI 512

typedef __attribute__((ext_vector_type(8))) short bfrag;   // 8 bf16 (4 VGPR)
typedef __attribute__((ext_vector_type(4))) float facc;    // 4 f32

__device__ __forceinline__ unsigned short f2bf(float f) {
  unsigned u = __float_as_uint(f);
  unsigned r = u + 0x7FFFu + ((u >> 16) & 1u);
  return (unsigned short)(r >> 16);
}
__device__ __forceinline__ float bf2f(unsigned short h) {
  return __uint_as_float(((unsigned)h) << 16);
}

__device__ __forceinline__ void gload16(const void* g, void* l) {
  __builtin_amdgcn_global_load_lds(
      (const __attribute__((address_space(1))) unsigned int*)g,
      (__attribute__((address_space(3))) unsigned int*)l, 16, 0, 0);
}

// ------------------------------------------------ split x -> padded bf16 hi/lo [B][S+2][C]
__global__ __launch_bounds__(256) void k_split_x(const float* __restrict__ x,
                                                 unsigned short* __restrict__ xph,
                                                 unsigned short* __restrict__ xpl) {
  const size_t total = (size_t)B_DIM * (S_LEN + 2) * C_DIM;
  size_t e0 = ((size_t)blockIdx.x * 256 + threadIdx.x) * 8;
  if (e0 >= total) return;
  int b = (int)(e0 / ((size_t)(S_LEN + 2) * C_DIM));
  size_t r = e0 - (size_t)b * (S_LEN + 2) * C_DIM;
  int sp = (int)(r / C_DIM);
  int c = (int)(r % C_DIM);
  unsigned short hv[8], lv[8];
  if (sp == 0 || sp == S_LEN + 1) {
#pragma unroll
    for (int j = 0; j < 8; ++j) { hv[j] = 0; lv[j] = 0; }
  } else {
    const float* xs = &x[((size_t)b * S_LEN + (sp - 1)) * C_DIM + c];
    float4 v0 = *(const float4*)xs;
    float4 v1 = *(const float4*)(xs + 4);
    float vv[8] = {v0.x, v0.y, v0.z, v0.w, v1.x, v1.y, v1.z, v1.w};
#pragma unroll
    for (int j = 0; j < 8; ++j) {
      unsigned short h = f2bf(vv[j]);
      hv[j] = h;
      lv[j] = f2bf(vv[j] - bf2f(h));
    }
  }
  *(uint4*)&xph[e0] = *(const uint4*)hv;
  *(uint4*)&xpl[e0] = *(const uint4*)lv;
}

// ------------------------------------------------ split w[co][ci][dk] -> wsp_{hi,lo}[dk][co][ci]
__global__ __launch_bounds__(256) void k_split_w(const float* __restrict__ w,
                                                 unsigned short* __restrict__ wh,
                                                 unsigned short* __restrict__ wl) {
  int idx = blockIdx.x * 256 + threadIdx.x;  // co*512+ci
  if (idx >= C_DIM * C_DIM) return;
  const float* src = &w[(size_t)idx * 3];
#pragma unroll
  for (int dk = 0; dk < 3; ++dk) {
    float v = src[dk];
    unsigned short h = f2bf(v);
    wh[(size_t)dk * (C_DIM * C_DIM) + idx] = h;
    wl[(size_t)dk * (C_DIM * C_DIM) + idx] = f2bf(v - bf2f(h));
  }
}

// ------------------------------------------------ fused conv(bf16x3 MFMA) + LN + GELU + proj + sigmoid
// 512 thr (8 waves, 2Mx4N), tile BM=128 x BN=512, BK=32. LDS rows = 128B (32 hi | 32 lo bf16),
// XOR-swizzled slot^=(row&7); linear LDS dest + pre-swizzled global source (rule #21).
__global__ __launch_bounds__(512, 2) void k_fused(const unsigned short* __restrict__ xph,
                                                  const unsigned short* __restrict__ xpl,
                                                  const unsigned short* __restrict__ wh,
                                                  const unsigned short* __restrict__ wl,
                                                  const float* __restrict__ conv_b,
                                                  const float* __restrict__ ln_g,
                                                  const float* __restrict__ ln_b,
                                                  const float* __restrict__ pw,
                                                  const float* __restrict__ pb,
                                                  const unsigned char* __restrict__ mask,
                                                  float* __restrict__ alpha) {
  __shared__ short At[128 * 64];   // 16 KB
  __shared__ short Bt[512 * 64];   // 64 KB

  const int t = threadIdx.x;
  const int lane = t & 63;
  const int wid = t >> 6;
  const int wr = wid >> 2;   // 0..1 (M): 64 rows each
  const int wc = wid & 3;    // 0..3 (N): 128 cols each
  const int lr = lane & 15;
  const int kg = lane >> 4;  // 0..3

  const int m0 = blockIdx.x * 128;
  const int b = m0 >> 12;
  const int s0 = m0 & (S_LEN - 1);

  // A staging: 2 chunks/thread, chunk c=r*512+t -> row=c>>3 (0..127), slot=(c&7)^(row&7)
  const unsigned short* asrc_base[2];
#pragma unroll
  for (int r = 0; r < 2; ++r) {
    int c = r * 512 + t;
    int row = c >> 3;
    int ls = (c & 7) ^ (row & 7);
    asrc_base[r] = (ls < 4 ? xph : xpl) + ((size_t)b * (S_LEN + 2) + (s0 + row)) * C_DIM + (ls & 3) * 8;
  }
  // B staging: 8 chunks c=r*512+t -> row=c>>3 (0..511)
  const unsigned short* bsrc_base[8];
#pragma unroll
  for (int r = 0; r < 8; ++r) {
    int c = r * 512 + t;
    int row = c >> 3;
    int ls = (c & 7) ^ (row & 7);
    bsrc_base[r] = (ls < 4 ? wh : wl) + (size_t)row * C_DIM + (ls & 3) * 8;
  }

  facc acc[4][8];
#pragma unroll
  for (int fm = 0; fm < 4; ++fm)
#pragma unroll
    for (int fn = 0; fn < 8; ++fn) acc[fm][fn] = (facc)0.f;

  for (int q = 0; q < 48; ++q) {
    const int dk = q >> 4;
    const int ci0 = (q & 15) << 5;
    __syncthreads();
#pragma unroll
    for (int r = 0; r < 2; ++r) gload16(asrc_base[r] + dk * C_DIM + ci0, &At[(r * 512 + t) * 8]);
    const size_t boff = (size_t)dk * (C_DIM * C_DIM) + ci0;
#pragma unroll
    for (int r = 0; r < 8; ++r) gload16(bsrc_base[r] + boff, &Bt[(r * 512 + t) * 8]);
    __syncthreads();

    bfrag ah[4], al[4];
#pragma unroll
    for (int fm = 0; fm < 4; ++fm) {
      int row = wr * 64 + fm * 16 + lr;
      int ph = kg ^ (row & 7);
      int pl = (4 + kg) ^ (row & 7);
      ah[fm] = *(const bfrag*)&At[row * 64 + ph * 8];
      al[fm] = *(const bfrag*)&At[row * 64 + pl * 8];
    }
#pragma unroll
    for (int fn = 0; fn < 8; ++fn) {
      int col = wc * 128 + fn * 16 + lr;
      int ph = kg ^ (col & 7);
      int pl = (4 + kg) ^ (col & 7);
      bfrag bh = *(const bfrag*)&Bt[col * 64 + ph * 8];
      bfrag bl = *(const bfrag*)&Bt[col * 64 + pl * 8];
#pragma unroll
      for (int fm = 0; fm < 4; ++fm) {
        acc[fm][fn] = __builtin_amdgcn_mfma_f32_16x16x32_bf16(ah[fm], bh, acc[fm][fn], 0, 0, 0);
        acc[fm][fn] = __builtin_amdgcn_mfma_f32_16x16x32_bf16(al[fm], bh, acc[fm][fn], 0, 0, 0);
        acc[fm][fn] = __builtin_amdgcn_mfma_f32_16x16x32_bf16(ah[fm], bl, acc[fm][fn], 0, 0, 0);
      }
    }
  }

  // ---------------- epilogue: bias + LN + GELU + proj + sigmoid (rows m0..m0+127)
  __syncthreads();
  float* red = (float*)At;          // [128][4]
  float* mrow = (float*)At + 512;   // [128]
  float* srow = (float*)At + 640;   // [128]

  float cb8[8], g8[8], be8[8], w8[8];
#pragma unroll
  for (int fn = 0; fn < 8; ++fn) {
    int col = wc * 128 + fn * 16 + lr;
    cb8[fn] = conv_b[col];
    g8[fn] = ln_g[col];
    be8[fn] = ln_b[col];
    w8[fn] = pw[col];
  }
#pragma unroll
  for (int fm = 0; fm < 4; ++fm)
#pragma unroll
    for (int fn = 0; fn < 8; ++fn)
#pragma unroll
      for (int j = 0; j < 4; ++j) acc[fm][fn][j] += cb8[fn];

  // pass 1: mean
#pragma unroll
  for (int fm = 0; fm < 4; ++fm)
#pragma unroll
    for (int j = 0; j < 4; ++j) {
      float s = 0.f;
#pragma unroll
      for (int fn = 0; fn < 8; ++fn) s += acc[fm][fn][j];
      s += __shfl_xor(s, 1, 64); s += __shfl_xor(s, 2, 64);
      s += __shfl_xor(s, 4, 64); s += __shfl_xor(s, 8, 64);
      if (lr == 0) red[(wr * 64 + fm * 16 + kg * 4 + j) * 4 + wc] = s;
    }
  __syncthreads();
  if (t < 128) mrow[t] = (red[t * 4] + red[t * 4 + 1] + red[t * 4 + 2] + red[t * 4 + 3]) * (1.f / 512.f);
  __syncthreads();
  float mu[4][4];
#pragma unroll
  for (int fm = 0; fm < 4; ++fm)
#pragma unroll
    for (int j = 0; j < 4; ++j) mu[fm][j] = mrow[wr * 64 + fm * 16 + kg * 4 + j];

  // pass 2: var
#pragma unroll
  for (int fm = 0; fm < 4; ++fm)
#pragma unroll
    for (int j = 0; j < 4; ++j) {
      float s = 0.f;
#pragma unroll
      for (int fn = 0; fn < 8; ++fn) {
        float d = acc[fm][fn][j] - mu[fm][j];
        s += d * d;
      }
      s += __shfl_xor(s, 1, 64); s += __shfl_xor(s, 2, 64);
      s += __shfl_xor(s, 4, 64); s += __shfl_xor(s, 8, 64);
      if (lr == 0) red[(wr * 64 + fm * 16 + kg * 4 + j) * 4 + wc] = s;
    }
  __syncthreads();
  if (t < 128) srow[t] = 1.0f / sqrtf((red[t * 4] + red[t * 4 + 1] + red[t * 4 + 2] + red[t * 4 + 3]) * (1.f / 512.f) + 1e-5f);
  __syncthreads();
  float rs[4][4];
#pragma unroll
  for (int fm = 0; fm < 4; ++fm)
#pragma unroll
    for (int j = 0; j < 4; ++j) rs[fm][j] = srow[wr * 64 + fm * 16 + kg * 4 + j];

  // pass 3: gelu + proj dot
#pragma unroll
  for (int fm = 0; fm < 4; ++fm)
#pragma unroll
    for (int j = 0; j < 4; ++j) {
      float s = 0.f;
#pragma unroll
      for (int fn = 0; fn < 8; ++fn) {
        float y = (acc[fm][fn][j] - mu[fm][j]) * rs[fm][j] * g8[fn] + be8[fn];
        float gel = 0.5f * y * (1.0f + erff(y * 0.70710678118654752440f));
        s += gel * w8[fn];
      }
      s += __shfl_xor(s, 1, 64); s += __shfl_xor(s, 2, 64);
      s += __shfl_xor(s, 4, 64); s += __shfl_xor(s, 8, 64);
      if (lr == 0) red[(wr * 64 + fm * 16 + kg * 4 + j) * 4 + wc] = s;
    }
  __syncthreads();
  if (t < 128) {
    float z = red[t * 4] + red[t * 4 + 1] + red[t * 4 + 2] + red[t * 4 + 3] + pb[0];
    float a = 1.f / (1.f + expf(-z));
    int pos = m0 + t;
    if (mask[pos]) a = 0.f;
    alpha[pos] = a;
  }
}

// ------------------------------------------------ per-batch alpha sum
__global__ __launch_bounds__(256) void k_asum(const float* __restrict__ alpha, float* __restrict__ asum) {
  __shared__ float red[256];
  const int b = blockIdx.x;
  const int t = threadIdx.x;
  float s = 0.f;
  for (int i = t; i < S_LEN; i += 256) s += alpha[(size_t)b * S_LEN + i];
  red[t] = s;
  __syncthreads();
  for (int k = 128; k > 0; k >>= 1) {
    if (t < k) red[t] += red[t + k];
    __syncthreads();
  }
  if (t == 0) asum[b] = red[0];
}

// ------------------------------------------------ sequential scan (matches np.cumsum order)
__global__ __launch_bounds__(256) void k_scan(const float* __restrict__ alpha,
                                              const float* __restrict__ asum,
                                              const int* __restrict__ tlen,
                                              float* __restrict__ alphaS,
                                              float* __restrict__ csum,
                                              int* __restrict__ ridx) {
  __shared__ float buf[B_DIM][257];
  __shared__ float cbuf[B_DIM][257];
  __shared__ int ibuf[B_DIM][257];
  __shared__ float run[B_DIM];
  __shared__ float scl[B_DIM];
  const int t = threadIdx.x;
  if (t < B_DIM) {
    run[t] = 0.f;
    float desired = 1.0f * (float)tlen[t] + 1e-4f;
    scl[t] = desired / asum[t];
  }
  __syncthreads();
  for (int c = 0; c < 16; ++c) {
#pragma unroll
    for (int r = 0; r < B_DIM; ++r)
      buf[r][t] = alpha[(size_t)r * S_LEN + c * 256 + t];
    __syncthreads();
    if (t < B_DIM) {
      float r = run[t];
      const float sc = scl[t];
      for (int ss = 0; ss < 256; ++ss) {
        float a = buf[t][ss] * sc;
        r += a;
        buf[t][ss] = a;
        cbuf[t][ss] = r;
        int ri = (int)floorf(r);
        ibuf[t][ss] = ri > TMAXI ? TMAXI : ri;
      }
      run[t] = r;
    }
    __syncthreads();
#pragma unroll
    for (int r = 0; r < B_DIM; ++r) {
      size_t g = (size_t)r * S_LEN + c * 256 + t;
      alphaS[g] = buf[r][t];
      csum[g] = cbuf[r][t];
      ridx[g] = ibuf[r][t];
    }
    __syncthreads();
  }
}

// ------------------------------------------------ scatter with atomics (no straggler)
// one wave per position; targets mirror the reference exactly
__global__ __launch_bounds__(256) void k_scatter(const float* __restrict__ x,
                                                 const float* __restrict__ alphaS,
                                                 const float* __restrict__ csum,
                                                 const int* __restrict__ ridx,
                                                 const int* __restrict__ tlen,
                                                 float* __restrict__ out) {
  const int w = threadIdx.x >> 6;
  const int lane = threadIdx.x & 63;
  const int p = blockIdx.x * 4 + w;  // 0..65535
  const int b = p >> 12;
  const int s = p & (S_LEN - 1);

  const int Rs = ridx[p];
  const int Ls = (s > 0) ? ridx[p - 1] : 0;
  const float a = alphaS[p];
  const float cs = csum[p];
  const int fire = Rs - Ls;
  const float rw = (fire > 0) ? (cs - (float)Rs) : 0.f;
  const int extra = (fire > 1) ? (fire - 1) : 0;
  const float lw = a - rw - (float)extra;
  const int tl = tlen[b];
  const int t1 = (Ls + 1 < TMAXI) ? (Ls + 1) : TMAXI;
  const int t2 = (t1 + 1 < TMAXI) ? (t1 + 1) : TMAXI;

  int rows[4];
  float wg[4];
  int n = 0;
  if (Ls < tl && lw != 0.f) { rows[n] = Ls; wg[n] = lw; ++n; }
  if (fire > 0 && Rs < tl && rw != 0.f) { rows[n] = Rs; wg[n] = rw; ++n; }
  if (extra >= 1 && t1 < tl) { rows[n] = t1; wg[n] = 1.0f; ++n; }
  if (extra >= 2 && t2 < tl) { rows[n] = t2; wg[n] = 1.0f; ++n; }
  if (n == 0) return;

  const float* xr = x + ((size_t)b * S_LEN + s) * C_DIM + lane * 8;
  float4 v0 = *(const float4*)xr;
  float4 v1 = *(const float4*)(xr + 4);

  for (int i = 0; i < n; ++i) {
    float* o = out + (((size_t)b * TMAXI) + rows[i]) * C_DIM + lane * 8;
    const float g = wg[i];
    unsafeAtomicAdd(&o[0], g * v0.x);
    unsafeAtomicAdd(&o[1], g * v0.y);
    unsafeAtomicAdd(&o[2], g * v0.z);
    unsafeAtomicAdd(&o[3], g * v0.w);
    unsafeAtomicAdd(&o[4], g * v1.x);
    unsafeAtomicAdd(&o[5], g * v1.y);
    unsafeAtomicAdd(&o[6], g * v1.z);
    unsafeAtomicAdd(&o[7], g * v1.w);
  }
}

// ---------------------------------------------------------------- launch
extern "C" void kernel_launch(void* const* d_in, const int* in_sizes, int n_in,
                              void* d_out, int out_size, void* d_ws, size_t ws_size,
                              hipStream_t stream) {
  const float* x = (const float*)d_in[0];
  const unsigned char* mask = (const unsigned char*)d_in[1];
  const int* tlen = (const int*)d_in[2];
  const float* conv_w = (const float*)d_in[3];
  const float* conv_b = (const float*)d_in[4];
  const float* ln_g = (const float*)d_in[5];
  const float* ln_b = (const float*)d_in[6];
  const float* proj_w = (const float*)d_in[7];
  const float* proj_b = (const float*)d_in[8];
  float* out = (float*)d_out;

  char* ws = (char*)d_ws;
  const size_t n_pos = (size_t)B_DIM * S_LEN;                    // 65536
  const size_t xp_elems = (size_t)B_DIM * (S_LEN + 2) * C_DIM;   // 33,570,816

  unsigned short* xph = (unsigned short*)ws;
  unsigned short* xpl = xph + xp_elems;
  unsigned short* wh = xpl + xp_elems;
  unsigned short* wl = wh + (size_t)3 * C_DIM * C_DIM;
  char* p = (char*)(wl + (size_t)3 * C_DIM * C_DIM);
  float* alpha = (float*)p;   p += n_pos * 4;
  float* alphaS = (float*)p;  p += n_pos * 4;
  float* csumb = (float*)p;   p += n_pos * 4;
  int* ridx = (int*)p;        p += n_pos * 4;
  float* asum = (float*)p;

  hipMemsetAsync(d_out, 0, (size_t)out_size * sizeof(float), stream);
  k_split_w<<<(C_DIM * C_DIM + 255) / 256, 256, 0, stream>>>(conv_w, wh, wl);
  k_split_x<<<(int)((xp_elems / 8 + 255) / 256), 256, 0, stream>>>(x, xph, xpl);
  k_fused<<<(B_DIM * S_LEN) / 128, 512, 0, stream>>>(xph, xpl, wh, wl, conv_b, ln_g, ln_b,
                                                     proj_w, proj_b, mask, alpha);
  k_asum<<<B_DIM, 256, 0, stream>>>(alpha, asum);
  k_scan<<<1, 256, 0, stream>>>(alpha, asum, tlen, alphaS, csumb, ridx);
  k_scatter<<<(B_DIM * S_LEN) / 4, 256, 0, stream>>>(x, alphaS, csumb, ridx, tlen, out);
}

// Round 8
// 1013.415 us; speedup vs baseline: 1.7815x; 1.7815x over previous
//
#include <hip/hip_runtime.h>
#include <math.h>

#define B_DIM 16
#define S_LEN 4096
#define C_DIM 512
#define TMAXI 512

typedef __attribute__((ext_vector_type(8))) short bfrag;   // 8 bf16 (4 VGPR)
typedef __attribute__((ext_vector_type(4))) float facc;    // 4 f32

__device__ __forceinline__ unsigned short f2bf(float f) {
  unsigned u = __float_as_uint(f);
  unsigned r = u + 0x7FFFu + ((u >> 16) & 1u);
  return (unsigned short)(r >> 16);
}
__device__ __forceinline__ float bf2f(unsigned short h) {
  return __uint_as_float(((unsigned)h) << 16);
}

__device__ __forceinline__ void gload16(const void* g, void* l) {
  __builtin_amdgcn_global_load_lds(
      (const __attribute__((address_space(1))) unsigned int*)g,
      (__attribute__((address_space(3))) unsigned int*)l, 16, 0, 0);
}

// ------------------------------------------------ split x -> padded bf16 hi/lo [B][S+2][C]
__global__ __launch_bounds__(256) void k_split_x(const float* __restrict__ x,
                                                 unsigned short* __restrict__ xph,
                                                 unsigned short* __restrict__ xpl) {
  const size_t total = (size_t)B_DIM * (S_LEN + 2) * C_DIM;
  size_t e0 = ((size_t)blockIdx.x * 256 + threadIdx.x) * 8;
  if (e0 >= total) return;
  int b = (int)(e0 / ((size_t)(S_LEN + 2) * C_DIM));
  size_t r = e0 - (size_t)b * (S_LEN + 2) * C_DIM;
  int sp = (int)(r / C_DIM);
  int c = (int)(r % C_DIM);
  unsigned short hv[8], lv[8];
  if (sp == 0 || sp == S_LEN + 1) {
#pragma unroll
    for (int j = 0; j < 8; ++j) { hv[j] = 0; lv[j] = 0; }
  } else {
    const float* xs = &x[((size_t)b * S_LEN + (sp - 1)) * C_DIM + c];
    float4 v0 = *(const float4*)xs;
    float4 v1 = *(const float4*)(xs + 4);
    float vv[8] = {v0.x, v0.y, v0.z, v0.w, v1.x, v1.y, v1.z, v1.w};
#pragma unroll
    for (int j = 0; j < 8; ++j) {
      unsigned short h = f2bf(vv[j]);
      hv[j] = h;
      lv[j] = f2bf(vv[j] - bf2f(h));
    }
  }
  *(uint4*)&xph[e0] = *(const uint4*)hv;
  *(uint4*)&xpl[e0] = *(const uint4*)lv;
}

// ------------------------------------------------ split w[co][ci][dk] -> wsp_{hi,lo}[dk][co][ci]
__global__ __launch_bounds__(256) void k_split_w(const float* __restrict__ w,
                                                 unsigned short* __restrict__ wh,
                                                 unsigned short* __restrict__ wl) {
  int idx = blockIdx.x * 256 + threadIdx.x;  // co*512+ci
  if (idx >= C_DIM * C_DIM) return;
  const float* src = &w[(size_t)idx * 3];
#pragma unroll
  for (int dk = 0; dk < 3; ++dk) {
    float v = src[dk];
    unsigned short h = f2bf(v);
    wh[(size_t)dk * (C_DIM * C_DIM) + idx] = h;
    wl[(size_t)dk * (C_DIM * C_DIM) + idx] = f2bf(v - bf2f(h));
  }
}

// ------------------------------------------------ fused conv(bf16x3 MFMA) + LN + GELU + proj + sigmoid
// 512 thr (8 waves, 2Mx4N), tile BM=64 x BN=512, BK=32 — proven 553us config (round 3).
__global__ __launch_bounds__(512) void k_fused(const unsigned short* __restrict__ xph,
                                               const unsigned short* __restrict__ xpl,
                                               const unsigned short* __restrict__ wh,
                                               const unsigned short* __restrict__ wl,
                                               const float* __restrict__ conv_b,
                                               const float* __restrict__ ln_g,
                                               const float* __restrict__ ln_b,
                                               const float* __restrict__ pw,
                                               const float* __restrict__ pb,
                                               const unsigned char* __restrict__ mask,
                                               float* __restrict__ alpha) {
  __shared__ short At[64 * 64];    // 8 KB
  __shared__ short Bt[512 * 64];   // 64 KB

  const int t = threadIdx.x;
  const int lane = t & 63;
  const int wid = t >> 6;
  const int wr = wid >> 2;   // 0..1 (M)
  const int wc = wid & 3;    // 0..3 (N)
  const int lr = lane & 15;
  const int kg = lane >> 4;  // 0..3

  const int m0 = blockIdx.x * 64;
  const int b = m0 >> 12;
  const int s0 = m0 & (S_LEN - 1);

  const int arow = t >> 3;
  const int aps = t & 7;
  const int als = aps ^ (arow & 7);
  const unsigned short* asrc_base =
      (als < 4 ? xph : xpl) + ((size_t)b * (S_LEN + 2) + (s0 + arow)) * C_DIM + (als & 3) * 8;

  const unsigned short* bsrc_base[8];
#pragma unroll
  for (int r = 0; r < 8; ++r) {
    int c = r * 512 + t;
    int row = c >> 3;
    int ls = (c & 7) ^ (row & 7);
    bsrc_base[r] = (ls < 4 ? wh : wl) + (size_t)row * C_DIM + (ls & 3) * 8;
  }

  facc acc[2][8];
#pragma unroll
  for (int fm = 0; fm < 2; ++fm)
#pragma unroll
    for (int fn = 0; fn < 8; ++fn) acc[fm][fn] = (facc)0.f;

  for (int q = 0; q < 48; ++q) {
    const int dk = q >> 4;
    const int ci0 = (q & 15) << 5;
    __syncthreads();
    gload16(asrc_base + dk * C_DIM + ci0, &At[t * 8]);
    const size_t boff = (size_t)dk * (C_DIM * C_DIM) + ci0;
#pragma unroll
    for (int r = 0; r < 8; ++r) gload16(bsrc_base[r] + boff, &Bt[(r * 512 + t) * 8]);
    __syncthreads();

    bfrag ah[2], al[2];
#pragma unroll
    for (int fm = 0; fm < 2; ++fm) {
      int row = wr * 32 + fm * 16 + lr;
      int ph = kg ^ (row & 7);
      int pl = (4 + kg) ^ (row & 7);
      ah[fm] = *(const bfrag*)&At[row * 64 + ph * 8];
      al[fm] = *(const bfrag*)&At[row * 64 + pl * 8];
    }
#pragma unroll
    for (int fn = 0; fn < 8; ++fn) {
      int col = wc * 128 + fn * 16 + lr;
      int ph = kg ^ (col & 7);
      int pl = (4 + kg) ^ (col & 7);
      bfrag bh = *(const bfrag*)&Bt[col * 64 + ph * 8];
      bfrag bl = *(const bfrag*)&Bt[col * 64 + pl * 8];
#pragma unroll
      for (int fm = 0; fm < 2; ++fm) {
        acc[fm][fn] = __builtin_amdgcn_mfma_f32_16x16x32_bf16(ah[fm], bh, acc[fm][fn], 0, 0, 0);
        acc[fm][fn] = __builtin_amdgcn_mfma_f32_16x16x32_bf16(al[fm], bh, acc[fm][fn], 0, 0, 0);
        acc[fm][fn] = __builtin_amdgcn_mfma_f32_16x16x32_bf16(ah[fm], bl, acc[fm][fn], 0, 0, 0);
      }
    }
  }

  // ---------------- epilogue: bias + LN + GELU + proj + sigmoid (rows m0..m0+63)
  __syncthreads();
  float* red = (float*)At;          // [64][4]
  float* mrow = (float*)At + 256;   // [64]
  float* srow = (float*)At + 320;   // [64]

  float cb8[8], g8[8], be8[8], w8[8];
#pragma unroll
  for (int fn = 0; fn < 8; ++fn) {
    int col = wc * 128 + fn * 16 + lr;
    cb8[fn] = conv_b[col];
    g8[fn] = ln_g[col];
    be8[fn] = ln_b[col];
    w8[fn] = pw[col];
  }
#pragma unroll
  for (int fm = 0; fm < 2; ++fm)
#pragma unroll
    for (int fn = 0; fn < 8; ++fn)
#pragma unroll
      for (int j = 0; j < 4; ++j) acc[fm][fn][j] += cb8[fn];

  // pass 1: mean
#pragma unroll
  for (int fm = 0; fm < 2; ++fm)
#pragma unroll
    for (int j = 0; j < 4; ++j) {
      float s = 0.f;
#pragma unroll
      for (int fn = 0; fn < 8; ++fn) s += acc[fm][fn][j];
      s += __shfl_xor(s, 1, 64); s += __shfl_xor(s, 2, 64);
      s += __shfl_xor(s, 4, 64); s += __shfl_xor(s, 8, 64);
      if (lr == 0) red[(wr * 32 + fm * 16 + kg * 4 + j) * 4 + wc] = s;
    }
  __syncthreads();
  if (t < 64) mrow[t] = (red[t * 4] + red[t * 4 + 1] + red[t * 4 + 2] + red[t * 4 + 3]) * (1.f / 512.f);
  __syncthreads();
  float mu[2][4];
#pragma unroll
  for (int fm = 0; fm < 2; ++fm)
#pragma unroll
    for (int j = 0; j < 4; ++j) mu[fm][j] = mrow[wr * 32 + fm * 16 + kg * 4 + j];

  // pass 2: var
#pragma unroll
  for (int fm = 0; fm < 2; ++fm)
#pragma unroll
    for (int j = 0; j < 4; ++j) {
      float s = 0.f;
#pragma unroll
      for (int fn = 0; fn < 8; ++fn) {
        float d = acc[fm][fn][j] - mu[fm][j];
        s += d * d;
      }
      s += __shfl_xor(s, 1, 64); s += __shfl_xor(s, 2, 64);
      s += __shfl_xor(s, 4, 64); s += __shfl_xor(s, 8, 64);
      if (lr == 0) red[(wr * 32 + fm * 16 + kg * 4 + j) * 4 + wc] = s;
    }
  __syncthreads();
  if (t < 64) srow[t] = 1.0f / sqrtf((red[t * 4] + red[t * 4 + 1] + red[t * 4 + 2] + red[t * 4 + 3]) * (1.f / 512.f) + 1e-5f);
  __syncthreads();
  float rs[2][4];
#pragma unroll
  for (int fm = 0; fm < 2; ++fm)
#pragma unroll
    for (int j = 0; j < 4; ++j) rs[fm][j] = srow[wr * 32 + fm * 16 + kg * 4 + j];

  // pass 3: gelu + proj dot
#pragma unroll
  for (int fm = 0; fm < 2; ++fm)
#pragma unroll
    for (int j = 0; j < 4; ++j) {
      float s = 0.f;
#pragma unroll
      for (int fn = 0; fn < 8; ++fn) {
        float y = (acc[fm][fn][j] - mu[fm][j]) * rs[fm][j] * g8[fn] + be8[fn];
        float gel = 0.5f * y * (1.0f + erff(y * 0.70710678118654752440f));
        s += gel * w8[fn];
      }
      s += __shfl_xor(s, 1, 64); s += __shfl_xor(s, 2, 64);
      s += __shfl_xor(s, 4, 64); s += __shfl_xor(s, 8, 64);
      if (lr == 0) red[(wr * 32 + fm * 16 + kg * 4 + j) * 4 + wc] = s;
    }
  __syncthreads();
  if (t < 64) {
    float z = red[t * 4] + red[t * 4 + 1] + red[t * 4 + 2] + red[t * 4 + 3] + pb[0];
    float a = 1.f / (1.f + expf(-z));
    int pos = m0 + t;
    if (mask[pos]) a = 0.f;
    alpha[pos] = a;
  }
}

// ------------------------------------------------ per-batch alpha sum
__global__ __launch_bounds__(256) void k_asum(const float* __restrict__ alpha, float* __restrict__ asum) {
  __shared__ float red[256];
  const int b = blockIdx.x;
  const int t = threadIdx.x;
  float s = 0.f;
  for (int i = t; i < S_LEN; i += 256) s += alpha[(size_t)b * S_LEN + i];
  red[t] = s;
  __syncthreads();
  for (int k = 128; k > 0; k >>= 1) {
    if (t < k) red[t] += red[t + k];
    __syncthreads();
  }
  if (t == 0) asum[b] = red[0];
}

// ------------------------------------------------ sequential scan (matches np.cumsum order)
__global__ __launch_bounds__(256) void k_scan(const float* __restrict__ alpha,
                                              const float* __restrict__ asum,
                                              const int* __restrict__ tlen,
                                              float* __restrict__ alphaS,
                                              float* __restrict__ csum,
                                              int* __restrict__ ridx) {
  __shared__ float buf[B_DIM][257];
  __shared__ float cbuf[B_DIM][257];
  __shared__ int ibuf[B_DIM][257];
  __shared__ float run[B_DIM];
  __shared__ float scl[B_DIM];
  const int t = threadIdx.x;
  if (t < B_DIM) {
    run[t] = 0.f;
    float desired = 1.0f * (float)tlen[t] + 1e-4f;
    scl[t] = desired / asum[t];
  }
  __syncthreads();
  for (int c = 0; c < 16; ++c) {
#pragma unroll
    for (int r = 0; r < B_DIM; ++r)
      buf[r][t] = alpha[(size_t)r * S_LEN + c * 256 + t];
    __syncthreads();
    if (t < B_DIM) {
      float r = run[t];
      const float sc = scl[t];
      for (int ss = 0; ss < 256; ++ss) {
        float a = buf[t][ss] * sc;
        r += a;
        buf[t][ss] = a;
        cbuf[t][ss] = r;
        int ri = (int)floorf(r);
        ibuf[t][ss] = ri > TMAXI ? TMAXI : ri;
      }
      run[t] = r;
    }
    __syncthreads();
#pragma unroll
    for (int r = 0; r < B_DIM; ++r) {
      size_t g = (size_t)r * S_LEN + c * 256 + t;
      alphaS[g] = buf[r][t];
      csum[g] = cbuf[r][t];
      ridx[g] = ibuf[r][t];
    }
    __syncthreads();
  }
}

// ------------------------------------------------ contributor-parallel gather (no atomics, no straggler)
__device__ __forceinline__ int lower_bound(const int* __restrict__ R, int v) {
  int lo = 0, hi = S_LEN;
  while (lo < hi) {
    int m = (lo + hi) >> 1;
    if (R[m] < v) lo = m + 1; else hi = m;
  }
  return lo;
}

__global__ __launch_bounds__(256) void k_out(const float* __restrict__ x,
                                             const float* __restrict__ alphaS,
                                             const float* __restrict__ csum,
                                             const int* __restrict__ ridx,
                                             const int* __restrict__ tlen,
                                             float* __restrict__ out) {
  __shared__ float part[4][512];
  const int b = blockIdx.y;
  const int tt = blockIdx.x;     // output row 0..511
  const int t = threadIdx.x;
  const int w = t >> 6;          // wave 0..3 splits contributor range
  const int lane = t & 63;       // 8 channels per lane

  float acc[8];
#pragma unroll
  for (int j = 0; j < 8; ++j) acc[j] = 0.f;

  if (tt < tlen[b]) {
    const int* R = ridx + (size_t)b * S_LEN;
    const float* aS = alphaS + (size_t)b * S_LEN;
    const float* cS = csum + (size_t)b * S_LEN;
    int lo = lower_bound(R, tt);
    int hi = lower_bound(R, tt + 1);
    if (hi > S_LEN - 1) hi = S_LEN - 1;
    const float* xb = x + ((size_t)b * S_LEN) * C_DIM + lane * 8;
    for (int s = lo + w; s <= hi; s += 4) {
      int Rs = R[s];
      int Ls = (s > 0) ? R[s - 1] : 0;
      int fire = Rs - Ls;
      float a = aS[s];
      float cs = cS[s];
      float rw = (fire > 0) ? (cs - (float)Rs) : 0.f;  // BETA=1
      int extra = (fire > 1) ? (fire - 1) : 0;
      float lw = a - rw - (float)extra;
      float wgt = 0.f;
      if (Ls == tt) wgt += lw;
      if (fire > 0 && Rs == tt) wgt += rw;
      int t1 = (Ls + 1 < TMAXI) ? (Ls + 1) : TMAXI;
      int t2 = (t1 + 1 < TMAXI) ? (t1 + 1) : TMAXI;
      if (extra >= 1 && t1 == tt) wgt += 1.0f;
      if (extra >= 2 && t2 == tt) wgt += 1.0f;
      if (wgt != 0.f) {
        const float4 v0 = *(const float4*)&xb[(size_t)s * C_DIM];
        const float4 v1 = *(const float4*)&xb[(size_t)s * C_DIM + 4];
        acc[0] = fmaf(wgt, v0.x, acc[0]);
        acc[1] = fmaf(wgt, v0.y, acc[1]);
        acc[2] = fmaf(wgt, v0.z, acc[2]);
        acc[3] = fmaf(wgt, v0.w, acc[3]);
        acc[4] = fmaf(wgt, v1.x, acc[4]);
        acc[5] = fmaf(wgt, v1.y, acc[5]);
        acc[6] = fmaf(wgt, v1.z, acc[6]);
        acc[7] = fmaf(wgt, v1.w, acc[7]);
      }
    }
  }
  // cross-wave reduce in LDS
  *(float4*)&part[w][lane * 8] = *(const float4*)&acc[0];
  *(float4*)&part[w][lane * 8 + 4] = *(const float4*)&acc[4];
  __syncthreads();
  const int c = t * 2;  // 256 threads x 2 channels
  float2 o;
  o.x = part[0][c] + part[1][c] + part[2][c] + part[3][c];
  o.y = part[0][c + 1] + part[1][c + 1] + part[2][c + 1] + part[3][c + 1];
  *(float2*)&out[(((size_t)b * TMAXI) + tt) * C_DIM + c] = o;
}

// ---------------------------------------------------------------- launch
extern "C" void kernel_launch(void* const* d_in, const int* in_sizes, int n_in,
                              void* d_out, int out_size, void* d_ws, size_t ws_size,
                              hipStream_t stream) {
  const float* x = (const float*)d_in[0];
  const unsigned char* mask = (const unsigned char*)d_in[1];
  const int* tlen = (const int*)d_in[2];
  const float* conv_w = (const float*)d_in[3];
  const float* conv_b = (const float*)d_in[4];
  const float* ln_g = (const float*)d_in[5];
  const float* ln_b = (const float*)d_in[6];
  const float* proj_w = (const float*)d_in[7];
  const float* proj_b = (const float*)d_in[8];
  float* out = (float*)d_out;

  char* ws = (char*)d_ws;
  const size_t n_pos = (size_t)B_DIM * S_LEN;                    // 65536
  const size_t xp_elems = (size_t)B_DIM * (S_LEN + 2) * C_DIM;   // 33,570,816

  unsigned short* xph = (unsigned short*)ws;
  unsigned short* xpl = xph + xp_elems;
  unsigned short* wh = xpl + xp_elems;
  unsigned short* wl = wh + (size_t)3 * C_DIM * C_DIM;
  char* p = (char*)(wl + (size_t)3 * C_DIM * C_DIM);
  float* alpha = (float*)p;   p += n_pos * 4;
  float* alphaS = (float*)p;  p += n_pos * 4;
  float* csumb = (float*)p;   p += n_pos * 4;
  int* ridx = (int*)p;        p += n_pos * 4;
  float* asum = (float*)p;

  k_split_w<<<(C_DIM * C_DIM + 255) / 256, 256, 0, stream>>>(conv_w, wh, wl);
  k_split_x<<<(int)((xp_elems / 8 + 255) / 256), 256, 0, stream>>>(x, xph, xpl);
  k_fused<<<(B_DIM * S_LEN) / 64, 512, 0, stream>>>(xph, xpl, wh, wl, conv_b, ln_g, ln_b,
                                                    proj_w, proj_b, mask, alpha);
  k_asum<<<B_DIM, 256, 0, stream>>>(alpha, asum);
  k_scan<<<1, 256, 0, stream>>>(alpha, asum, tlen, alphaS, csumb, ridx);
  k_out<<<dim3(TMAXI, B_DIM), 256, 0, stream>>>(x, alphaS, csumb, ridx, tlen, out);
}